// Round 15
// baseline (123.425 us; speedup 1.0000x reference)
//
#include <hip/hip_runtime.h>
#include <math.h>

#define BB 32
#define TT 512
#define FF 512
#define HH 1024
#define CC 1000
#define QQ (4*HH)    // 4096 gate columns
#define FCB 8
#define KCN 4

// ---------------- persistent fused kernel (config A) ----------------
#define NBLK 320     // 64 h0-blocks + 256 data-blocks; <= 2 blocks/CU x 256 CUs
#define PJCH 32      // h0 rows per chunk (32 chunks)
#define PCHH 32
#define PJCD 32      // data rows per chunk (16 chunks)
#define PCHD 16

__device__ __forceinline__ void gbar(int* cnt) {
    __syncthreads();
    if (threadIdx.x == 0) {
        __threadfence();                        // release: wb L2 (agent scope)
        atomicAdd(cnt, 1);
        while (atomicAdd(cnt, 0) < NBLK) __builtin_amdgcn_s_sleep(2);
        __threadfence();                        // acquire: inv stale L1/L2
    }
    __syncthreads();
}

__global__ __launch_bounds__(512, 4) void k_fused(
    const float* __restrict__ data, const float* __restrict__ h0,
    const float* __restrict__ c0,
    const float* __restrict__ wf, const float* __restrict__ wi,
    const float* __restrict__ wc, const float* __restrict__ wo,
    const float* __restrict__ fcw, const float* __restrict__ fcb,
    float* __restrict__ hp, float* __restrict__ dp,
    float* __restrict__ hl, float* __restrict__ pl,
    float* __restrict__ out, int* __restrict__ bars)
{
    __shared__ __align__(16) float smem[48*257];   // 49.3 KB arena (max = P3)
    const int t   = threadIdx.x;
    const int blk = blockIdx.x;

    // ===================== P1: gate partials (320 blocks) =====================
    if (blk < 2*PCHH) {
        // ---- h0 part: 2048 cols/block, PJCH rows ----
        const int cb2 = blk & 1;
        const int ch  = blk >> 1;
        const int q   = cb2*2048 + t*4;
        const int gate = q >> 10;             // wave-uniform
        const int k4   = q & (HH-1);
        const float* w = (gate==0) ? wf : (gate==1) ? wi : (gate==2) ? wc : wo;
        if (t < PJCH) smem[t] = h0[ch*PJCH + t];
        __syncthreads();
        float4 s = make_float4(0.f,0.f,0.f,0.f);
        #pragma unroll
        for (int j = 0; j < PJCH; j += 4) {
            const float4 w0 = *(const float4*)(w + (size_t)(ch*PJCH + j+0)*HH + k4);
            const float4 w1 = *(const float4*)(w + (size_t)(ch*PJCH + j+1)*HH + k4);
            const float4 w2 = *(const float4*)(w + (size_t)(ch*PJCH + j+2)*HH + k4);
            const float4 w3 = *(const float4*)(w + (size_t)(ch*PJCH + j+3)*HH + k4);
            const float h0v = smem[j+0], h1v = smem[j+1], h2v = smem[j+2], h3v = smem[j+3];
            s.x += h0v*w0.x; s.y += h0v*w0.y; s.z += h0v*w0.z; s.w += h0v*w0.w;
            s.x += h1v*w1.x; s.y += h1v*w1.y; s.z += h1v*w1.z; s.w += h1v*w1.w;
            s.x += h2v*w2.x; s.y += h2v*w2.y; s.z += h2v*w2.z; s.w += h2v*w2.w;
            s.x += h3v*w3.x; s.y += h3v*w3.y; s.z += h3v*w3.z; s.w += h3v*w3.w;
        }
        *(float4*)(hp + (size_t)ch*QQ + q) = s;
    } else {
        // ---- data part: 256 cols x 32 batches, PJCD rows ----
        const int idx  = blk - 2*PCHH;
        const int cb   = idx & 15;
        const int cd   = idx >> 4;
        const int q0   = cb*256;
        const int gate = q0 >> 10;
        const int k0   = q0 & (HH-1);
        const float* w = (gate==0) ? wf : (gate==1) ? wi : (gate==2) ? wc : wo;
        const int jc0  = cd*PJCD;

        for (int sl = t; sl < BB*PJCD/4; sl += 512) {
            const int b  = sl / (PJCD/4);
            const int jj = (sl % (PJCD/4))*4;
            const float4 v = *(const float4*)(data + (size_t)b*TT*FF + (size_t)(TT-1)*FF + jc0 + jj);
            smem[b*PJCD + jj+0] = v.x; smem[b*PJCD + jj+1] = v.y;
            smem[b*PJCD + jj+2] = v.z; smem[b*PJCD + jj+3] = v.w;
        }
        __syncthreads();

        const int c4 = t & 63;
        const int b0 = (t >> 6) * 4;
        const int k4 = k0 + c4*4;
        float4 acc[4];
        #pragma unroll
        for (int bi = 0; bi < 4; ++bi) acc[bi] = make_float4(0.f,0.f,0.f,0.f);
        #pragma unroll 2
        for (int j = 0; j < PJCD; j += 4) {
            const float4 w0 = *(const float4*)(w + (size_t)(HH + jc0 + j+0)*HH + k4);
            const float4 w1 = *(const float4*)(w + (size_t)(HH + jc0 + j+1)*HH + k4);
            const float4 w2 = *(const float4*)(w + (size_t)(HH + jc0 + j+2)*HH + k4);
            const float4 w3 = *(const float4*)(w + (size_t)(HH + jc0 + j+3)*HH + k4);
            #pragma unroll
            for (int bi = 0; bi < 4; ++bi) {
                const float d0 = smem[(b0+bi)*PJCD + j+0];
                const float d1 = smem[(b0+bi)*PJCD + j+1];
                const float d2 = smem[(b0+bi)*PJCD + j+2];
                const float d3 = smem[(b0+bi)*PJCD + j+3];
                acc[bi].x += d0*w0.x; acc[bi].y += d0*w0.y; acc[bi].z += d0*w0.z; acc[bi].w += d0*w0.w;
                acc[bi].x += d1*w1.x; acc[bi].y += d1*w1.y; acc[bi].z += d1*w1.z; acc[bi].w += d1*w1.w;
                acc[bi].x += d2*w2.x; acc[bi].y += d2*w2.y; acc[bi].z += d2*w2.z; acc[bi].w += d2*w2.w;
                acc[bi].x += d3*w3.x; acc[bi].y += d3*w3.y; acc[bi].z += d3*w3.z; acc[bi].w += d3*w3.w;
            }
        }
        #pragma unroll
        for (int bi = 0; bi < 4; ++bi)
            *(float4*)(dp + ((size_t)cd*BB + b0 + bi)*QQ + q0 + c4*4) = acc[bi];
    }
    gbar(bars + 0);

    // ===================== P2: reduce + cell (64 blocks x 2 units) =====================
    if (blk < 64) {
        float4* p = (float4*)smem;            // [2][4][64]
        const int sh = t >> 8;
        const int tt = t & 255;
        const int unit = blk*2 + sh;          // 0..127
        const int kblk = unit & 3;
        const int b    = unit >> 2;
        const int g = tt >> 6, i = tt & 63;
        const int q = g*HH + kblk*256 + i*4;

        float4 s = make_float4(0.f,0.f,0.f,0.f);
        #pragma unroll 8
        for (int ch = 0; ch < PCHH; ++ch) {
            const float4 v = *(const float4*)(hp + (size_t)ch*QQ + q);
            s.x += v.x; s.y += v.y; s.z += v.z; s.w += v.w;
        }
        #pragma unroll 8
        for (int cd = 0; cd < PCHD; ++cd) {
            const float4 v = *(const float4*)(dp + ((size_t)cd*BB + b)*QQ + q);
            s.x += v.x; s.y += v.y; s.z += v.z; s.w += v.w;
        }
        p[sh*256 + g*64 + i] = s;
        __syncthreads();

        if (tt < 64) {
            const float4 gf = p[sh*256 +   0 + tt], gi = p[sh*256 +  64 + tt];
            const float4 gc = p[sh*256 + 128 + tt], go = p[sh*256 + 192 + tt];
            const float4 cv = *(const float4*)(c0 + kblk*256 + tt*4);
            float4 h;
            {
                const float f = 1.f/(1.f + expf(-gf.x)), ii = 1.f/(1.f + expf(-gi.x));
                const float cg = tanhf(gc.x), o = 1.f/(1.f + expf(-go.x));
                h.x = o*tanhf(f*cv.x + ii*cg);
            }
            {
                const float f = 1.f/(1.f + expf(-gf.y)), ii = 1.f/(1.f + expf(-gi.y));
                const float cg = tanhf(gc.y), o = 1.f/(1.f + expf(-go.y));
                h.y = o*tanhf(f*cv.y + ii*cg);
            }
            {
                const float f = 1.f/(1.f + expf(-gf.z)), ii = 1.f/(1.f + expf(-gi.z));
                const float cg = tanhf(gc.z), o = 1.f/(1.f + expf(-go.z));
                h.z = o*tanhf(f*cv.z + ii*cg);
            }
            {
                const float f = 1.f/(1.f + expf(-gf.w)), ii = 1.f/(1.f + expf(-gi.w));
                const float cg = tanhf(gc.w), o = 1.f/(1.f + expf(-go.w));
                h.w = o*tanhf(f*cv.w + ii*cg);
            }
            *(float4*)(hl + (size_t)b*HH + kblk*256 + tt*4) = h;
        }
    }
    gbar(bars + 1);

    // ===================== P3: fc partial GEMM (252 blocks) =====================
    if (blk < 252) {
        float* hs = smem;                     // [32][257]
        float* wl = smem + 32*257;            // [16][257]
        const int cxp = blk >> 2;             // 0..62
        const int kc  = blk & 3;
        const int cb0 = cxp*16;
        const int k0  = kc*256;

        for (int l = t; l < 32*64; l += 512) {
            const int bb = l >> 6, kk = l & 63;
            const float4 v = *(const float4*)(hl + (size_t)bb*HH + k0 + kk*4);
            hs[bb*257 + kk*4+0] = v.x; hs[bb*257 + kk*4+1] = v.y;
            hs[bb*257 + kk*4+2] = v.z; hs[bb*257 + kk*4+3] = v.w;
        }
        for (int l = t; l < 16*64; l += 512) {
            const int cc = l >> 6, kk = l & 63;
            if (cb0 + cc < CC) {
                const float4 v = *(const float4*)(fcw + (size_t)(cb0+cc)*HH + k0 + kk*4);
                wl[cc*257 + kk*4+0] = v.x; wl[cc*257 + kk*4+1] = v.y;
                wl[cc*257 + kk*4+2] = v.z; wl[cc*257 + kk*4+3] = v.w;
            }
        }
        __syncthreads();

        const int b  = t & 31;
        const int cl = t >> 5;                // 0..15
        const int c  = cb0 + cl;
        float acc = 0.f;
        #pragma unroll 16
        for (int k = 0; k < 256; ++k)
            acc += hs[b*257 + k] * wl[cl*257 + k];
        if (c < CC) pl[((size_t)kc*BB + b)*CC + c] = acc;
    }
    gbar(bars + 2);

    // ===================== P4: reduce + bias + relu + log_softmax (16 blocks x 2 rows) =====================
    if (blk < 16) {
        float* red = smem;                    // [2][10]
        const int sh = t >> 8;
        const int tt = t & 255;
        const int b  = blk*2 + sh;
        float v[4]; float vmax = -1e30f;
        #pragma unroll
        for (int ci = 0; ci < 4; ++ci) {
            const int c = tt + ci*256;
            if (c < CC) {
                float s = pl[((size_t)0*BB + b)*CC + c]
                        + pl[((size_t)1*BB + b)*CC + c]
                        + pl[((size_t)2*BB + b)*CC + c]
                        + pl[((size_t)3*BB + b)*CC + c]
                        + fcb[c];
                v[ci] = fmaxf(s, 0.f);
                vmax = fmaxf(vmax, v[ci]);
            } else v[ci] = -1e30f;
        }
        for (int o = 32; o > 0; o >>= 1) vmax = fmaxf(vmax, __shfl_down(vmax, o, 64));
        const int lane = tt & 63, wid = tt >> 6;
        if (lane == 0) red[sh*10 + wid] = vmax;
        __syncthreads();
        if (tt == 0)
            red[sh*10 + 8] = fmaxf(fmaxf(red[sh*10+0], red[sh*10+1]),
                                   fmaxf(red[sh*10+2], red[sh*10+3]));
        __syncthreads();
        const float m = red[sh*10 + 8];
        float se = 0.f;
        #pragma unroll
        for (int ci = 0; ci < 4; ++ci) {
            const int c = tt + ci*256;
            if (c < CC) se += expf(v[ci] - m);
        }
        for (int o = 32; o > 0; o >>= 1) se += __shfl_down(se, o, 64);
        if (lane == 0) red[sh*10 + wid] = se;
        __syncthreads();
        if (tt == 0)
            red[sh*10 + 9] = m + logf(red[sh*10+0] + red[sh*10+1] + red[sh*10+2] + red[sh*10+3]);
        __syncthreads();
        const float lse = red[sh*10 + 9];
        #pragma unroll
        for (int ci = 0; ci < 4; ++ci) {
            const int c = tt + ci*256;
            if (c < CC) out[(size_t)b*CC + c] = v[ci] - lse;
        }
    }
}

// ================= fallback path (round-14 structure, small ws) =================
template<int JCH, int CHH, int JCD, int CHD>
__global__ __launch_bounds__(512, 4) void k_gates(
    const float* __restrict__ data, const float* __restrict__ h0,
    const float* __restrict__ wf, const float* __restrict__ wi,
    const float* __restrict__ wc, const float* __restrict__ wo,
    float* __restrict__ hp, float* __restrict__ dp)
{
    constexpr int LDSN = (BB*JCD > JCH) ? BB*JCD : JCH;
    __shared__ float lds[LDSN];
    const int t  = threadIdx.x;
    const int bx = blockIdx.x;
    constexpr int NH0 = 2*CHH;
    if (bx < NH0) {
        const int cb2 = bx & 1, ch = bx >> 1;
        const int q = cb2*2048 + t*4;
        const int gate = q >> 10, k4 = q & (HH-1);
        const float* w = (gate==0) ? wf : (gate==1) ? wi : (gate==2) ? wc : wo;
        if (t < JCH) lds[t] = h0[ch*JCH + t];
        __syncthreads();
        float4 s = make_float4(0.f,0.f,0.f,0.f);
        #pragma unroll
        for (int j = 0; j < JCH; ++j) {
            const float4 wv = *(const float4*)(w + (size_t)(ch*JCH + j)*HH + k4);
            const float hv = lds[j];
            s.x += hv*wv.x; s.y += hv*wv.y; s.z += hv*wv.z; s.w += hv*wv.w;
        }
        *(float4*)(hp + (size_t)ch*QQ + q) = s;
    } else {
        const int idx = bx - NH0;
        const int cb = idx & 15, cd = idx >> 4;
        const int q0 = cb*256;
        const int gate = q0 >> 10, k0 = q0 & (HH-1);
        const float* w = (gate==0) ? wf : (gate==1) ? wi : (gate==2) ? wc : wo;
        const int jc0 = cd*JCD;
        for (int s = t; s < BB*JCD/4; s += 512) {
            const int b = s / (JCD/4), jj = (s % (JCD/4))*4;
            const float4 v = *(const float4*)(data + (size_t)b*TT*FF + (size_t)(TT-1)*FF + jc0 + jj);
            lds[b*JCD + jj+0] = v.x; lds[b*JCD + jj+1] = v.y;
            lds[b*JCD + jj+2] = v.z; lds[b*JCD + jj+3] = v.w;
        }
        __syncthreads();
        const int c4 = t & 63, b0 = (t >> 6)*4;
        const int k4 = k0 + c4*4;
        float4 acc[4];
        #pragma unroll
        for (int bi = 0; bi < 4; ++bi) acc[bi] = make_float4(0.f,0.f,0.f,0.f);
        for (int j = 0; j < JCD; ++j) {
            const float4 wv = *(const float4*)(w + (size_t)(HH + jc0 + j)*HH + k4);
            #pragma unroll
            for (int bi = 0; bi < 4; ++bi) {
                const float dv = lds[(b0+bi)*JCD + j];
                acc[bi].x += dv*wv.x; acc[bi].y += dv*wv.y;
                acc[bi].z += dv*wv.z; acc[bi].w += dv*wv.w;
            }
        }
        #pragma unroll
        for (int bi = 0; bi < 4; ++bi)
            *(float4*)(dp + ((size_t)cd*BB + b0 + bi)*QQ + q0 + c4*4) = acc[bi];
    }
}

template<int CH, int CD>
__global__ __launch_bounds__(256, 2) void k_cell(
    const float* __restrict__ hp, const float* __restrict__ dp,
    const float* __restrict__ c0, float* __restrict__ hlast)
{
    __shared__ float4 p[4][64];
    const int t = threadIdx.x, kblk = blockIdx.x, b = blockIdx.y;
    const int g = t >> 6, i = t & 63;
    const int q = g*HH + kblk*256 + i*4;
    float4 s = make_float4(0.f,0.f,0.f,0.f);
    #pragma unroll 8
    for (int ch = 0; ch < CH; ++ch) {
        const float4 v = *(const float4*)(hp + (size_t)ch*QQ + q);
        s.x += v.x; s.y += v.y; s.z += v.z; s.w += v.w;
    }
    #pragma unroll 8
    for (int cd = 0; cd < CD; ++cd) {
        const float4 v = *(const float4*)(dp + ((size_t)cd*BB + b)*QQ + q);
        s.x += v.x; s.y += v.y; s.z += v.z; s.w += v.w;
    }
    p[g][i] = s;
    __syncthreads();
    if (t < 64) {
        const float4 gf = p[0][t], gi = p[1][t], gc = p[2][t], go = p[3][t];
        const float4 cv = *(const float4*)(c0 + kblk*256 + t*4);
        float4 h;
        { const float f=1.f/(1.f+expf(-gf.x)), ii=1.f/(1.f+expf(-gi.x)), cg=tanhf(gc.x), o=1.f/(1.f+expf(-go.x)); h.x=o*tanhf(f*cv.x+ii*cg); }
        { const float f=1.f/(1.f+expf(-gf.y)), ii=1.f/(1.f+expf(-gi.y)), cg=tanhf(gc.y), o=1.f/(1.f+expf(-go.y)); h.y=o*tanhf(f*cv.y+ii*cg); }
        { const float f=1.f/(1.f+expf(-gf.z)), ii=1.f/(1.f+expf(-gi.z)), cg=tanhf(gc.z), o=1.f/(1.f+expf(-go.z)); h.z=o*tanhf(f*cv.z+ii*cg); }
        { const float f=1.f/(1.f+expf(-gf.w)), ii=1.f/(1.f+expf(-gi.w)), cg=tanhf(gc.w), o=1.f/(1.f+expf(-go.w)); h.w=o*tanhf(f*cv.w+ii*cg); }
        *(float4*)(hlast + (size_t)b*HH + kblk*256 + t*4) = h;
    }
}

__global__ __launch_bounds__(256) void k_fc_part(
    const float* __restrict__ hlast, const float* __restrict__ fcw,
    float* __restrict__ pl)
{
    __shared__ float hs[BB][257];
    __shared__ float wl[FCB][257];
    const int t = threadIdx.x;
    const int c0 = blockIdx.x * FCB;
    const int kc = blockIdx.y;
    const int k0 = kc*256;
    const int b = t & 31, cl = t >> 5;
    const int c = c0 + cl;
    for (int l = t; l < BB*64; l += 256) {
        const int bb = l >> 6, kk = l & 63;
        const float4 v = *(const float4*)(hlast + (size_t)bb*HH + k0 + kk*4);
        hs[bb][kk*4+0] = v.x; hs[bb][kk*4+1] = v.y;
        hs[bb][kk*4+2] = v.z; hs[bb][kk*4+3] = v.w;
    }
    for (int l = t; l < FCB*64; l += 256) {
        const int cc = l >> 6, kk = l & 63;
        const float4 v = *(const float4*)(fcw + (size_t)(c0+cc)*HH + k0 + kk*4);
        wl[cc][kk*4+0] = v.x; wl[cc][kk*4+1] = v.y;
        wl[cc][kk*4+2] = v.z; wl[cc][kk*4+3] = v.w;
    }
    __syncthreads();
    float acc = 0.f;
    #pragma unroll 16
    for (int k = 0; k < 256; ++k) acc += hs[b][k] * wl[cl][k];
    pl[((size_t)kc*BB + b)*CC + c] = acc;
}

__global__ __launch_bounds__(256) void k_lsm(
    const float* __restrict__ pl, const float* __restrict__ fcb,
    float* __restrict__ out)
{
    __shared__ float red[8];
    const int b = blockIdx.x, t = threadIdx.x;
    float v[4]; float vmax = -1e30f;
    #pragma unroll
    for (int ci = 0; ci < 4; ++ci) {
        const int c = t + ci*256;
        if (c < CC) {
            float s = pl[((size_t)0*BB + b)*CC + c] + pl[((size_t)1*BB + b)*CC + c]
                    + pl[((size_t)2*BB + b)*CC + c] + pl[((size_t)3*BB + b)*CC + c] + fcb[c];
            v[ci] = fmaxf(s, 0.f);
            vmax = fmaxf(vmax, v[ci]);
        } else v[ci] = -1e30f;
    }
    for (int o = 32; o > 0; o >>= 1) vmax = fmaxf(vmax, __shfl_down(vmax, o, 64));
    const int lane = t & 63, wid = t >> 6;
    if (lane == 0) red[wid] = vmax;
    __syncthreads();
    if (t == 0) red[4] = fmaxf(fmaxf(red[0], red[1]), fmaxf(red[2], red[3]));
    __syncthreads();
    const float m = red[4];
    float se = 0.f;
    #pragma unroll
    for (int ci = 0; ci < 4; ++ci) {
        const int c = t + ci*256;
        if (c < CC) se += expf(v[ci] - m);
    }
    for (int o = 32; o > 0; o >>= 1) se += __shfl_down(se, o, 64);
    if (lane == 0) red[wid] = se;
    __syncthreads();
    if (t == 0) red[5] = m + logf(red[0] + red[1] + red[2] + red[3]);
    __syncthreads();
    const float lse = red[5];
    #pragma unroll
    for (int ci = 0; ci < 4; ++ci) {
        const int c = t + ci*256;
        if (c < CC) out[(size_t)b*CC + c] = v[ci] - lse;
    }
}

extern "C" void kernel_launch(void* const* d_in, const int* in_sizes, int n_in,
                              void* d_out, int out_size, void* d_ws, size_t ws_size,
                              hipStream_t stream) {
    const float* data = (const float*)d_in[0];
    const float* h0   = (const float*)d_in[1];
    const float* c0   = (const float*)d_in[2];
    const float* wf   = (const float*)d_in[3];
    const float* wi   = (const float*)d_in[4];
    const float* wc   = (const float*)d_in[5];
    const float* wo   = (const float*)d_in[6];
    const float* fcw  = (const float*)d_in[7];
    const float* fcb  = (const float*)d_in[8];
    float* out = (float*)d_out;

    // ws layout: [0..63] barrier counters; then hp, dp, hl, pl (float4-aligned).
    int*   bars = (int*)d_ws;
    float* hp = (float*)d_ws + 16;                    // PCHH*QQ
    float* dp = hp + (size_t)PCHH*QQ;                 // PCHD*BB*QQ
    float* hl = dp + (size_t)PCHD*BB*QQ;              // BB*HH
    float* pl = hl + (size_t)BB*HH;                   // KCN*BB*CC
    const size_t need = (16 + (size_t)PCHH*QQ + (size_t)PCHD*BB*QQ
                         + (size_t)BB*HH + (size_t)KCN*BB*CC) * 4;

    if (ws_size >= need) {
        hipMemsetAsync(bars, 0, 16, stream);
        k_fused<<<dim3(NBLK), 512, 0, stream>>>(data, h0, c0, wf, wi, wc, wo,
                                                fcw, fcb, hp, dp, hl, pl, out, bars);
    } else {
        // fallback: 4-kernel path, small footprint (CH_D=4, JCD=128)
        float* hpB = (float*)d_ws;                    // 32*QQ
        float* dpB = hpB + (size_t)32*QQ;             // 4*BB*QQ
        float* hlB = dpB + (size_t)4*BB*QQ;           // BB*HH
        float* plB = hlB + (size_t)BB*HH;             // KCN*BB*CC
        k_gates<32,32,128,4><<<dim3(2*32 + 16*4), 512, 0, stream>>>(data, h0, wf, wi, wc, wo, hpB, dpB);
        k_cell<32,4><<<dim3(HH/256, BB), 256, 0, stream>>>(hpB, dpB, c0, hlB);
        k_fc_part<<<dim3(CC/FCB, KCN), 256, 0, stream>>>(hlB, fcw, plB);
        k_lsm<<<dim3(BB), 256, 0, stream>>>(plB, fcb, out);
    }
}

// Round 16
// 83.818 us; speedup vs baseline: 1.4725x; 1.4725x over previous
//
#include <hip/hip_runtime.h>
#include <math.h>

#define BB 32
#define TT 512
#define FF 512
#define HH 1024
#define CC 1000
#define QQ (4*HH)    // 4096 gate columns
#define FCB 8        // fc columns per block

// ---------------- Stage 1 (fused): gate partials, 512-thread blocks ----------------
// First 2*CHH blocks: h0 part (2048 cols/block, JCH rows/chunk).
// Next 16*CHD blocks: data part (256 cols x 32 batches, JCD rows/chunk).
template<int JCH, int CHH, int JCD, int CHD>
__global__ __launch_bounds__(512, 4) void k_gates(
    const float* __restrict__ data, const float* __restrict__ h0,
    const float* __restrict__ wf, const float* __restrict__ wi,
    const float* __restrict__ wc, const float* __restrict__ wo,
    float* __restrict__ hp, float* __restrict__ dp)
{
    constexpr int LDSN = (BB*JCD > JCH) ? BB*JCD : JCH;
    __shared__ float lds[LDSN];
    const int t  = threadIdx.x;
    const int bx = blockIdx.x;
    constexpr int NH0 = 2*CHH;

    if (bx < NH0) {
        // ---- h0 part: 2048 cols, JCH rows per chunk ----
        const int cb2 = bx & 1;               // 2048-col half
        const int ch  = bx >> 1;              // row chunk
        const int q   = cb2*2048 + t*4;       // global gate col
        const int gate = q >> 10;             // wave-uniform
        const int k4   = q & (HH-1);
        const float* w = (gate==0) ? wf : (gate==1) ? wi : (gate==2) ? wc : wo;
        if (t < JCH) lds[t] = h0[ch*JCH + t];
        __syncthreads();
        float4 s = make_float4(0.f,0.f,0.f,0.f);
        #pragma unroll
        for (int j = 0; j < JCH; j += 4) {
            const float4 w0 = *(const float4*)(w + (size_t)(ch*JCH + j+0)*HH + k4);
            const float4 w1 = *(const float4*)(w + (size_t)(ch*JCH + j+1)*HH + k4);
            const float4 w2 = *(const float4*)(w + (size_t)(ch*JCH + j+2)*HH + k4);
            const float4 w3 = *(const float4*)(w + (size_t)(ch*JCH + j+3)*HH + k4);
            const float h0v = lds[j+0], h1v = lds[j+1], h2v = lds[j+2], h3v = lds[j+3];
            s.x += h0v*w0.x; s.y += h0v*w0.y; s.z += h0v*w0.z; s.w += h0v*w0.w;
            s.x += h1v*w1.x; s.y += h1v*w1.y; s.z += h1v*w1.z; s.w += h1v*w1.w;
            s.x += h2v*w2.x; s.y += h2v*w2.y; s.z += h2v*w2.z; s.w += h2v*w2.w;
            s.x += h3v*w3.x; s.y += h3v*w3.y; s.z += h3v*w3.z; s.w += h3v*w3.w;
        }
        *(float4*)(hp + (size_t)ch*QQ + q) = s;
    } else {
        // ---- data part ----
        const int idx  = bx - NH0;
        const int cb   = idx & 15;            // 256-col block
        const int cd   = idx >> 4;            // j-chunk
        const int q0   = cb*256;
        const int gate = q0 >> 10;            // block-uniform
        const int k0   = q0 & (HH-1);
        const float* w = (gate==0) ? wf : (gate==1) ? wi : (gate==2) ? wc : wo;
        const int jc0  = cd*JCD;

        for (int s = t; s < BB*JCD/4; s += 512) {
            const int b  = s / (JCD/4);
            const int jj = (s % (JCD/4))*4;
            const float4 v = *(const float4*)(data + (size_t)b*TT*FF + (size_t)(TT-1)*FF + jc0 + jj);
            lds[b*JCD + jj+0] = v.x; lds[b*JCD + jj+1] = v.y;
            lds[b*JCD + jj+2] = v.z; lds[b*JCD + jj+3] = v.w;
        }
        __syncthreads();

        const int c4 = t & 63;                // 4-col group
        const int b0 = (t >> 6) * 4;          // 4-batch group
        const int k4 = k0 + c4*4;
        float4 acc[4];
        #pragma unroll
        for (int bi = 0; bi < 4; ++bi) acc[bi] = make_float4(0.f,0.f,0.f,0.f);

        #pragma unroll 2
        for (int j = 0; j < JCD; j += 4) {
            const float4 w0 = *(const float4*)(w + (size_t)(HH + jc0 + j+0)*HH + k4);
            const float4 w1 = *(const float4*)(w + (size_t)(HH + jc0 + j+1)*HH + k4);
            const float4 w2 = *(const float4*)(w + (size_t)(HH + jc0 + j+2)*HH + k4);
            const float4 w3 = *(const float4*)(w + (size_t)(HH + jc0 + j+3)*HH + k4);
            #pragma unroll
            for (int bi = 0; bi < 4; ++bi) {
                const float d0 = lds[(b0+bi)*JCD + j+0];
                const float d1 = lds[(b0+bi)*JCD + j+1];
                const float d2 = lds[(b0+bi)*JCD + j+2];
                const float d3 = lds[(b0+bi)*JCD + j+3];
                acc[bi].x += d0*w0.x; acc[bi].y += d0*w0.y; acc[bi].z += d0*w0.z; acc[bi].w += d0*w0.w;
                acc[bi].x += d1*w1.x; acc[bi].y += d1*w1.y; acc[bi].z += d1*w1.z; acc[bi].w += d1*w1.w;
                acc[bi].x += d2*w2.x; acc[bi].y += d2*w2.y; acc[bi].z += d2*w2.z; acc[bi].w += d2*w2.w;
                acc[bi].x += d3*w3.x; acc[bi].y += d3*w3.y; acc[bi].z += d3*w3.z; acc[bi].w += d3*w3.w;
            }
        }
        #pragma unroll
        for (int bi = 0; bi < 4; ++bi)
            *(float4*)(dp + ((size_t)cd*BB + b0 + bi)*QQ + q0 + c4*4) = acc[bi];
    }
}

// ---------------- Stage 2: reduce partials + gates -> h_last ----------------
// grid = (HH/256 = 4, BB), block = 256. Block (0,0) also resets the fc ticket.
template<int CH, int CD>
__global__ __launch_bounds__(256, 2) void k_cell(
    const float* __restrict__ hp, const float* __restrict__ dp,
    const float* __restrict__ c0, float* __restrict__ hlast,
    int* __restrict__ ticket)
{
    __shared__ float4 p[4][64];
    const int t    = threadIdx.x;
    const int kblk = blockIdx.x;
    const int b    = blockIdx.y;
    if (kblk == 0 && b == 0 && t == 0) atomicExch(ticket, 0);
    const int g = t >> 6, i = t & 63;
    const int q = g*HH + kblk*256 + i*4;

    float4 s = make_float4(0.f,0.f,0.f,0.f);
    #pragma unroll 8
    for (int ch = 0; ch < CH; ++ch) {
        const float4 v = *(const float4*)(hp + (size_t)ch*QQ + q);
        s.x += v.x; s.y += v.y; s.z += v.z; s.w += v.w;
    }
    #pragma unroll 8
    for (int cd = 0; cd < CD; ++cd) {
        const float4 v = *(const float4*)(dp + ((size_t)cd*BB + b)*QQ + q);
        s.x += v.x; s.y += v.y; s.z += v.z; s.w += v.w;
    }
    p[g][i] = s;
    __syncthreads();

    if (t < 64) {
        const float4 gf = p[0][t], gi = p[1][t], gc = p[2][t], go = p[3][t];
        const float4 cv = *(const float4*)(c0 + kblk*256 + t*4);
        float4 h;
        { const float f=1.f/(1.f+expf(-gf.x)), ii=1.f/(1.f+expf(-gi.x)), cg=tanhf(gc.x), o=1.f/(1.f+expf(-go.x)); h.x=o*tanhf(f*cv.x+ii*cg); }
        { const float f=1.f/(1.f+expf(-gf.y)), ii=1.f/(1.f+expf(-gi.y)), cg=tanhf(gc.y), o=1.f/(1.f+expf(-go.y)); h.y=o*tanhf(f*cv.y+ii*cg); }
        { const float f=1.f/(1.f+expf(-gf.z)), ii=1.f/(1.f+expf(-gi.z)), cg=tanhf(gc.z), o=1.f/(1.f+expf(-go.z)); h.z=o*tanhf(f*cv.z+ii*cg); }
        { const float f=1.f/(1.f+expf(-gf.w)), ii=1.f/(1.f+expf(-gi.w)), cg=tanhf(gc.w), o=1.f/(1.f+expf(-go.w)); h.w=o*tanhf(f*cv.w+ii*cg); }
        *(float4*)(hlast + (size_t)b*HH + kblk*256 + t*4) = h;
    }
}

// ---------------- Stage 3: fc GEMM + last-block log_softmax ----------------
// grid = (CC/FCB = 125), block = 256. Full-k, 257-pad conflict-free scalar LDS
// inner loop (round-5-proven). Writes relu'd logits to out. Each block then
// fences + takes a ticket; the 125th block does the 32-row log_softmax in
// place with MLP-friendly unrolled loads (round-6's mechanism, fixed tail).
__global__ __launch_bounds__(256) void k_fc_tail(
    const float* __restrict__ hlast, const float* __restrict__ fcw,
    const float* __restrict__ fcb, float* __restrict__ out,
    int* __restrict__ ticket)
{
    __shared__ float hs[BB][257];
    __shared__ float wl[FCB][257];
    __shared__ int lastFlag;
    const int t  = threadIdx.x;
    const int c0 = blockIdx.x * FCB;
    const int b  = t & 31;
    const int cl = t >> 5;
    const int c  = c0 + cl;
    float acc = 0.f;
    #pragma unroll
    for (int kc = 0; kc < HH/256; ++kc) {
        const int k0 = kc*256;
        for (int l = t; l < BB*64; l += 256) {
            const int bb = l >> 6, kk = l & 63;
            const float4 v = *(const float4*)(hlast + (size_t)bb*HH + k0 + kk*4);
            hs[bb][kk*4+0] = v.x; hs[bb][kk*4+1] = v.y;
            hs[bb][kk*4+2] = v.z; hs[bb][kk*4+3] = v.w;
        }
        for (int l = t; l < FCB*64; l += 256) {
            const int cc = l >> 6, kk = l & 63;
            const float4 v = *(const float4*)(fcw + (size_t)(c0+cc)*HH + k0 + kk*4);
            wl[cc][kk*4+0] = v.x; wl[cc][kk*4+1] = v.y;
            wl[cc][kk*4+2] = v.z; wl[cc][kk*4+3] = v.w;
        }
        __syncthreads();
        #pragma unroll 16
        for (int k = 0; k < 256; ++k)
            acc += hs[b][k] * wl[cl][k];
        __syncthreads();
    }
    out[(size_t)b*CC + c] = fmaxf(acc + fcb[c], 0.f);

    // ---- single-sync last-block handoff ----
    __syncthreads();                          // all stores in this block issued
    if (t == 0) {
        __threadfence();                      // release our logit writes (agent scope)
        lastFlag = (atomicAdd(ticket, 1) == (int)gridDim.x - 1);
    }
    __syncthreads();
    if (!lastFlag) return;
    __threadfence();                          // acquire all blocks' logit writes

    // ---- 32-row log_softmax, 8 lanes per row, unrolled independent loads ----
    const int rb = t >> 3;                    // row (batch) 0..31
    const int l8 = t & 7;                     // lane within row
    float vm = -1e30f;
    #pragma unroll 8
    for (int i = 0; i < 125; ++i)
        vm = fmaxf(vm, out[(size_t)rb*CC + l8 + i*8]);
    vm = fmaxf(vm, __shfl_xor(vm, 1, 64));
    vm = fmaxf(vm, __shfl_xor(vm, 2, 64));
    vm = fmaxf(vm, __shfl_xor(vm, 4, 64));
    float se = 0.f;
    #pragma unroll 8
    for (int i = 0; i < 125; ++i)
        se += expf(out[(size_t)rb*CC + l8 + i*8] - vm);
    se += __shfl_xor(se, 1, 64);
    se += __shfl_xor(se, 2, 64);
    se += __shfl_xor(se, 4, 64);
    const float lse = vm + logf(se);
    #pragma unroll 8
    for (int i = 0; i < 125; ++i) {
        const size_t idx = (size_t)rb*CC + l8 + i*8;
        out[idx] = out[idx] - lse;
    }
}

extern "C" void kernel_launch(void* const* d_in, const int* in_sizes, int n_in,
                              void* d_out, int out_size, void* d_ws, size_t ws_size,
                              hipStream_t stream) {
    const float* data = (const float*)d_in[0];
    const float* h0   = (const float*)d_in[1];
    const float* c0   = (const float*)d_in[2];
    const float* wf   = (const float*)d_in[3];
    const float* wi   = (const float*)d_in[4];
    const float* wc   = (const float*)d_in[5];
    const float* wo   = (const float*)d_in[6];
    const float* fcw  = (const float*)d_in[7];
    const float* fcb  = (const float*)d_in[8];
    float* out = (float*)d_out;

    // ws layout: [16 ints ticket] hp, dp, hl.
    // Config A: CH_H=32 (JCH=32), CH_D=16 (JCD=32) -> ~9.1 MB.
    // Config B: CH_H=32 (JCH=32), CH_D=4  (JCD=128) -> ~2.8 MB (fallback).
    int*   tk = (int*)d_ws;
    float* base = (float*)d_ws + 16;
    const size_t needA = (16 + (size_t)32*QQ + (size_t)16*BB*QQ + (size_t)BB*HH) * 4;
    const bool cfgA = (ws_size >= needA);

    if (cfgA) {
        float* hp = base;                             // 32*QQ
        float* dp = hp + (size_t)32*QQ;               // 16*BB*QQ
        float* hl = dp + (size_t)16*BB*QQ;            // BB*HH
        k_gates<32,32,32,16><<<dim3(2*32 + 16*16), 512, 0, stream>>>(data, h0, wf, wi, wc, wo, hp, dp);
        k_cell<32,16><<<dim3(HH/256, BB), 256, 0, stream>>>(hp, dp, c0, hl, tk);
        k_fc_tail<<<dim3(CC/FCB), 256, 0, stream>>>(hl, fcw, fcb, out, tk);
    } else {
        float* hp = base;                             // 32*QQ
        float* dp = hp + (size_t)32*QQ;               // 4*BB*QQ
        float* hl = dp + (size_t)4*BB*QQ;             // BB*HH
        k_gates<32,32,128,4><<<dim3(2*32 + 16*4), 512, 0, stream>>>(data, h0, wf, wi, wc, wo, hp, dp);
        k_cell<32,4><<<dim3(HH/256, BB), 256, 0, stream>>>(hp, dp, c0, hl, tk);
        k_fc_tail<<<dim3(CC/FCB), 256, 0, stream>>>(hl, fcw, fcb, out, tk);
    }
}

// Round 17
// 31.735 us; speedup vs baseline: 3.8893x; 2.6412x over previous
//
#include <hip/hip_runtime.h>
#include <math.h>

#define BB 32
#define TT 512
#define FF 512
#define HH 1024
#define CC 1000
#define QQ (4*HH)    // 4096 gate columns
#define FCB 8        // fc columns per block
#define KCN 4        // fc k-split chunks

// ---------------- Stage 1 (fused): gate partials, 512-thread blocks ----------------
// First 2*CHH blocks: h0 part (2048 cols/block, JCH rows/chunk).
// Next 16*CHD blocks: data part (256 cols x 32 batches, JCD rows/chunk).
template<int JCH, int CHH, int JCD, int CHD>
__global__ __launch_bounds__(512, 4) void k_gates(
    const float* __restrict__ data, const float* __restrict__ h0,
    const float* __restrict__ wf, const float* __restrict__ wi,
    const float* __restrict__ wc, const float* __restrict__ wo,
    float* __restrict__ hp, float* __restrict__ dp)
{
    constexpr int LDSN = (BB*JCD > JCH) ? BB*JCD : JCH;
    __shared__ float lds[LDSN];
    const int t  = threadIdx.x;
    const int bx = blockIdx.x;
    constexpr int NH0 = 2*CHH;

    if (bx < NH0) {
        // ---- h0 part: 2048 cols, JCH rows per chunk ----
        const int cb2 = bx & 1;               // 2048-col half
        const int ch  = bx >> 1;              // row chunk
        const int q   = cb2*2048 + t*4;       // global gate col
        const int gate = q >> 10;             // wave-uniform
        const int k4   = q & (HH-1);
        const float* w = (gate==0) ? wf : (gate==1) ? wi : (gate==2) ? wc : wo;
        if (t < JCH) lds[t] = h0[ch*JCH + t];
        __syncthreads();
        float4 s = make_float4(0.f,0.f,0.f,0.f);
        #pragma unroll
        for (int j = 0; j < JCH; j += 4) {
            const float4 w0 = *(const float4*)(w + (size_t)(ch*JCH + j+0)*HH + k4);
            const float4 w1 = *(const float4*)(w + (size_t)(ch*JCH + j+1)*HH + k4);
            const float4 w2 = *(const float4*)(w + (size_t)(ch*JCH + j+2)*HH + k4);
            const float4 w3 = *(const float4*)(w + (size_t)(ch*JCH + j+3)*HH + k4);
            const float h0v = lds[j+0], h1v = lds[j+1], h2v = lds[j+2], h3v = lds[j+3];
            s.x += h0v*w0.x; s.y += h0v*w0.y; s.z += h0v*w0.z; s.w += h0v*w0.w;
            s.x += h1v*w1.x; s.y += h1v*w1.y; s.z += h1v*w1.z; s.w += h1v*w1.w;
            s.x += h2v*w2.x; s.y += h2v*w2.y; s.z += h2v*w2.z; s.w += h2v*w2.w;
            s.x += h3v*w3.x; s.y += h3v*w3.y; s.z += h3v*w3.z; s.w += h3v*w3.w;
        }
        *(float4*)(hp + (size_t)ch*QQ + q) = s;
    } else {
        // ---- data part ----
        const int idx  = bx - NH0;
        const int cb   = idx & 15;            // 256-col block
        const int cd   = idx >> 4;            // j-chunk
        const int q0   = cb*256;
        const int gate = q0 >> 10;            // block-uniform
        const int k0   = q0 & (HH-1);
        const float* w = (gate==0) ? wf : (gate==1) ? wi : (gate==2) ? wc : wo;
        const int jc0  = cd*JCD;

        for (int s = t; s < BB*JCD/4; s += 512) {
            const int b  = s / (JCD/4);
            const int jj = (s % (JCD/4))*4;
            const float4 v = *(const float4*)(data + (size_t)b*TT*FF + (size_t)(TT-1)*FF + jc0 + jj);
            lds[b*JCD + jj+0] = v.x; lds[b*JCD + jj+1] = v.y;
            lds[b*JCD + jj+2] = v.z; lds[b*JCD + jj+3] = v.w;
        }
        __syncthreads();

        const int c4 = t & 63;                // 4-col group
        const int b0 = (t >> 6) * 4;          // 4-batch group
        const int k4 = k0 + c4*4;
        float4 acc[4];
        #pragma unroll
        for (int bi = 0; bi < 4; ++bi) acc[bi] = make_float4(0.f,0.f,0.f,0.f);

        #pragma unroll 2
        for (int j = 0; j < JCD; j += 4) {
            const float4 w0 = *(const float4*)(w + (size_t)(HH + jc0 + j+0)*HH + k4);
            const float4 w1 = *(const float4*)(w + (size_t)(HH + jc0 + j+1)*HH + k4);
            const float4 w2 = *(const float4*)(w + (size_t)(HH + jc0 + j+2)*HH + k4);
            const float4 w3 = *(const float4*)(w + (size_t)(HH + jc0 + j+3)*HH + k4);
            #pragma unroll
            for (int bi = 0; bi < 4; ++bi) {
                const float d0 = lds[(b0+bi)*JCD + j+0];
                const float d1 = lds[(b0+bi)*JCD + j+1];
                const float d2 = lds[(b0+bi)*JCD + j+2];
                const float d3 = lds[(b0+bi)*JCD + j+3];
                acc[bi].x += d0*w0.x; acc[bi].y += d0*w0.y; acc[bi].z += d0*w0.z; acc[bi].w += d0*w0.w;
                acc[bi].x += d1*w1.x; acc[bi].y += d1*w1.y; acc[bi].z += d1*w1.z; acc[bi].w += d1*w1.w;
                acc[bi].x += d2*w2.x; acc[bi].y += d2*w2.y; acc[bi].z += d2*w2.z; acc[bi].w += d2*w2.w;
                acc[bi].x += d3*w3.x; acc[bi].y += d3*w3.y; acc[bi].z += d3*w3.z; acc[bi].w += d3*w3.w;
            }
        }
        #pragma unroll
        for (int bi = 0; bi < 4; ++bi)
            *(float4*)(dp + ((size_t)cd*BB + b0 + bi)*QQ + q0 + c4*4) = acc[bi];
    }
}

// ---------------- Stage 2: reduce partials + gates -> h_last ----------------
// grid = (HH/256 = 4, BB), block = 256.
template<int CH, int CD>
__global__ __launch_bounds__(256, 2) void k_cell(
    const float* __restrict__ hp, const float* __restrict__ dp,
    const float* __restrict__ c0, float* __restrict__ hlast)
{
    __shared__ float4 p[4][64];
    const int t    = threadIdx.x;
    const int kblk = blockIdx.x;
    const int b    = blockIdx.y;
    const int g    = t >> 6;
    const int i    = t & 63;
    const int q    = g*HH + kblk*256 + i*4;

    float4 s = make_float4(0.f,0.f,0.f,0.f);
    #pragma unroll 8
    for (int ch = 0; ch < CH; ++ch) {
        const float4 v = *(const float4*)(hp + (size_t)ch*QQ + q);
        s.x += v.x; s.y += v.y; s.z += v.z; s.w += v.w;
    }
    #pragma unroll 8
    for (int cd = 0; cd < CD; ++cd) {
        const float4 v = *(const float4*)(dp + ((size_t)cd*BB + b)*QQ + q);
        s.x += v.x; s.y += v.y; s.z += v.z; s.w += v.w;
    }
    p[g][i] = s;
    __syncthreads();

    if (t < 64) {
        const float4 gf = p[0][t], gi = p[1][t], gc = p[2][t], go = p[3][t];
        const float4 cv = *(const float4*)(c0 + kblk*256 + t*4);
        float4 h;
        { const float f=1.f/(1.f+expf(-gf.x)), ii=1.f/(1.f+expf(-gi.x)), cg=tanhf(gc.x), o=1.f/(1.f+expf(-go.x)); h.x=o*tanhf(f*cv.x+ii*cg); }
        { const float f=1.f/(1.f+expf(-gf.y)), ii=1.f/(1.f+expf(-gi.y)), cg=tanhf(gc.y), o=1.f/(1.f+expf(-go.y)); h.y=o*tanhf(f*cv.y+ii*cg); }
        { const float f=1.f/(1.f+expf(-gf.z)), ii=1.f/(1.f+expf(-gi.z)), cg=tanhf(gc.z), o=1.f/(1.f+expf(-go.z)); h.z=o*tanhf(f*cv.z+ii*cg); }
        { const float f=1.f/(1.f+expf(-gf.w)), ii=1.f/(1.f+expf(-gi.w)), cg=tanhf(gc.w), o=1.f/(1.f+expf(-go.w)); h.w=o*tanhf(f*cv.w+ii*cg); }
        *(float4*)(hlast + (size_t)b*HH + kblk*256 + t*4) = h;
    }
}

// ---------------- Stage 3a: fc partial GEMM (k-split) ----------------
// grid = (CC/FCB = 125, KCN = 4), block = 256. 258-pad -> float2 LDS reads
// (ds_read_b64; 2-way bank aliasing = free), half the LDS instruction count
// of the scalar version. Partial -> pl[(kc*BB + b)*CC + c].
__global__ __launch_bounds__(256) void k_fc_part(
    const float* __restrict__ hlast, const float* __restrict__ fcw,
    float* __restrict__ pl)
{
    __shared__ float hs[BB][258];
    __shared__ float wl[FCB][258];
    const int t  = threadIdx.x;
    const int c0 = blockIdx.x * FCB;
    const int kc = blockIdx.y;
    const int k0 = kc*256;
    const int b  = t & 31;
    const int cl = t >> 5;
    const int c  = c0 + cl;

    for (int l = t; l < BB*64; l += 256) {
        const int bb = l >> 6, kk = l & 63;
        const float4 v = *(const float4*)(hlast + (size_t)bb*HH + k0 + kk*4);
        *(float2*)&hs[bb][kk*4+0] = make_float2(v.x, v.y);
        *(float2*)&hs[bb][kk*4+2] = make_float2(v.z, v.w);
    }
    for (int l = t; l < FCB*64; l += 256) {
        const int cc = l >> 6, kk = l & 63;
        const float4 v = *(const float4*)(fcw + (size_t)(c0+cc)*HH + k0 + kk*4);
        *(float2*)&wl[cc][kk*4+0] = make_float2(v.x, v.y);
        *(float2*)&wl[cc][kk*4+2] = make_float2(v.z, v.w);
    }
    __syncthreads();

    float acc = 0.f;
    #pragma unroll 16
    for (int k2 = 0; k2 < 128; ++k2) {
        const float2 h2 = *(const float2*)&hs[b][k2*2];
        const float2 w2 = *(const float2*)&wl[cl][k2*2];
        acc += h2.x*w2.x + h2.y*w2.y;
    }
    pl[((size_t)kc*BB + b)*CC + c] = acc;
}

// ---------------- Stage 3b: reduce k-split + bias + relu + log_softmax ----------------
// grid = (BB), block = 256.
__global__ __launch_bounds__(256) void k_lsm(
    const float* __restrict__ pl, const float* __restrict__ fcb,
    float* __restrict__ out)
{
    __shared__ float red[8];
    const int b = blockIdx.x, t = threadIdx.x;
    float v[4]; float vmax = -1e30f;
    #pragma unroll
    for (int ci = 0; ci < 4; ++ci) {
        const int c = t + ci*256;
        if (c < CC) {
            float s = pl[((size_t)0*BB + b)*CC + c]
                    + pl[((size_t)1*BB + b)*CC + c]
                    + pl[((size_t)2*BB + b)*CC + c]
                    + pl[((size_t)3*BB + b)*CC + c]
                    + fcb[c];
            v[ci] = fmaxf(s, 0.f);
            vmax = fmaxf(vmax, v[ci]);
        } else v[ci] = -1e30f;
    }
    for (int o = 32; o > 0; o >>= 1) vmax = fmaxf(vmax, __shfl_down(vmax, o, 64));
    const int lane = t & 63, wid = t >> 6;
    if (lane == 0) red[wid] = vmax;
    __syncthreads();
    if (t == 0) red[4] = fmaxf(fmaxf(red[0], red[1]), fmaxf(red[2], red[3]));
    __syncthreads();
    const float m = red[4];
    float se = 0.f;
    #pragma unroll
    for (int ci = 0; ci < 4; ++ci) {
        const int c = t + ci*256;
        if (c < CC) se += expf(v[ci] - m);
    }
    for (int o = 32; o > 0; o >>= 1) se += __shfl_down(se, o, 64);
    if (lane == 0) red[wid] = se;
    __syncthreads();
    if (t == 0) red[5] = m + logf(red[0] + red[1] + red[2] + red[3]);
    __syncthreads();
    const float lse = red[5];
    #pragma unroll
    for (int ci = 0; ci < 4; ++ci) {
        const int c = t + ci*256;
        if (c < CC) out[(size_t)b*CC + c] = v[ci] - lse;
    }
}

extern "C" void kernel_launch(void* const* d_in, const int* in_sizes, int n_in,
                              void* d_out, int out_size, void* d_ws, size_t ws_size,
                              hipStream_t stream) {
    const float* data = (const float*)d_in[0];
    const float* h0   = (const float*)d_in[1];
    const float* c0   = (const float*)d_in[2];
    const float* wf   = (const float*)d_in[3];
    const float* wi   = (const float*)d_in[4];
    const float* wc   = (const float*)d_in[5];
    const float* wo   = (const float*)d_in[6];
    const float* fcw  = (const float*)d_in[7];
    const float* fcb  = (const float*)d_in[8];
    float* out = (float*)d_out;

    // Config A: CH_H=32 (JCH=32), CH_D=16 (JCD=32) -> ~9.1 MB ws.
    // Config B: CH_H=32 (JCH=32), CH_D=4  (JCD=128) -> ~3.2 MB ws (fallback).
    const size_t needA = ((size_t)32*QQ + (size_t)16*BB*QQ + (size_t)BB*HH + (size_t)KCN*BB*CC) * 4;
    const bool cfgA = (ws_size >= needA);

    float* ws = (float*)d_ws;
    if (cfgA) {
        float* hp = ws;                               // 32*QQ
        float* dp = hp + (size_t)32*QQ;               // 16*BB*QQ
        float* hl = dp + (size_t)16*BB*QQ;            // BB*HH
        float* pl = hl + (size_t)BB*HH;               // KCN*BB*CC
        k_gates<32,32,32,16><<<dim3(2*32 + 16*16), 512, 0, stream>>>(data, h0, wf, wi, wc, wo, hp, dp);
        k_cell<32,16><<<dim3(HH/256, BB), 256, 0, stream>>>(hp, dp, c0, hl);
        k_fc_part<<<dim3(CC/FCB, KCN), 256, 0, stream>>>(hl, fcw, pl);
        k_lsm<<<dim3(BB), 256, 0, stream>>>(pl, fcb, out);
    } else {
        float* hp = ws;                               // 32*QQ
        float* dp = hp + (size_t)32*QQ;               // 4*BB*QQ
        float* hl = dp + (size_t)4*BB*QQ;             // BB*HH
        float* pl = hl + (size_t)BB*HH;               // KCN*BB*CC
        k_gates<32,32,128,4><<<dim3(2*32 + 16*4), 512, 0, stream>>>(data, h0, wf, wi, wc, wo, hp, dp);
        k_cell<32,4><<<dim3(HH/256, BB), 256, 0, stream>>>(hp, dp, c0, hl);
        k_fc_part<<<dim3(CC/FCB, KCN), 256, 0, stream>>>(hl, fcw, pl);
        k_lsm<<<dim3(BB), 256, 0, stream>>>(pl, fcb, out);
    }
}

// Round 18
// 31.598 us; speedup vs baseline: 3.9061x; 1.0043x over previous
//
#include <hip/hip_runtime.h>
#include <math.h>

#define BB 32
#define TT 512
#define FF 512
#define HH 1024
#define CC 1000
#define QQ (4*HH)    // 4096 gate columns
#define FCB 8        // fc columns per block
#define KCN 8        // fc k-split chunks
#define KS  (HH/KCN) // 128 k per chunk

// ---------------- Stage 1 (fused): gate partials, 512-thread blocks ----------------
// First 2*CHH blocks: h0 part (2048 cols/block, JCH rows/chunk).
// Next 16*CHD blocks: data part (256 cols x 32 batches, JCD rows/chunk).
template<int JCH, int CHH, int JCD, int CHD>
__global__ __launch_bounds__(512, 4) void k_gates(
    const float* __restrict__ data, const float* __restrict__ h0,
    const float* __restrict__ wf, const float* __restrict__ wi,
    const float* __restrict__ wc, const float* __restrict__ wo,
    float* __restrict__ hp, float* __restrict__ dp)
{
    constexpr int LDSN = (BB*JCD > JCH) ? BB*JCD : JCH;
    __shared__ float lds[LDSN];
    const int t  = threadIdx.x;
    const int bx = blockIdx.x;
    constexpr int NH0 = 2*CHH;

    if (bx < NH0) {
        // ---- h0 part: 2048 cols, JCH rows per chunk ----
        const int cb2 = bx & 1;               // 2048-col half
        const int ch  = bx >> 1;              // row chunk
        const int q   = cb2*2048 + t*4;       // global gate col
        const int gate = q >> 10;             // wave-uniform
        const int k4   = q & (HH-1);
        const float* w = (gate==0) ? wf : (gate==1) ? wi : (gate==2) ? wc : wo;
        if (t < JCH) lds[t] = h0[ch*JCH + t];
        __syncthreads();
        float4 s = make_float4(0.f,0.f,0.f,0.f);
        #pragma unroll
        for (int j = 0; j < JCH; j += 4) {
            const float4 w0 = *(const float4*)(w + (size_t)(ch*JCH + j+0)*HH + k4);
            const float4 w1 = *(const float4*)(w + (size_t)(ch*JCH + j+1)*HH + k4);
            const float4 w2 = *(const float4*)(w + (size_t)(ch*JCH + j+2)*HH + k4);
            const float4 w3 = *(const float4*)(w + (size_t)(ch*JCH + j+3)*HH + k4);
            const float h0v = lds[j+0], h1v = lds[j+1], h2v = lds[j+2], h3v = lds[j+3];
            s.x += h0v*w0.x; s.y += h0v*w0.y; s.z += h0v*w0.z; s.w += h0v*w0.w;
            s.x += h1v*w1.x; s.y += h1v*w1.y; s.z += h1v*w1.z; s.w += h1v*w1.w;
            s.x += h2v*w2.x; s.y += h2v*w2.y; s.z += h2v*w2.z; s.w += h2v*w2.w;
            s.x += h3v*w3.x; s.y += h3v*w3.y; s.z += h3v*w3.z; s.w += h3v*w3.w;
        }
        *(float4*)(hp + (size_t)ch*QQ + q) = s;
    } else {
        // ---- data part ----
        const int idx  = bx - NH0;
        const int cb   = idx & 15;            // 256-col block
        const int cd   = idx >> 4;            // j-chunk
        const int q0   = cb*256;
        const int gate = q0 >> 10;            // block-uniform
        const int k0   = q0 & (HH-1);
        const float* w = (gate==0) ? wf : (gate==1) ? wi : (gate==2) ? wc : wo;
        const int jc0  = cd*JCD;

        for (int s = t; s < BB*JCD/4; s += 512) {
            const int b  = s / (JCD/4);
            const int jj = (s % (JCD/4))*4;
            const float4 v = *(const float4*)(data + (size_t)b*TT*FF + (size_t)(TT-1)*FF + jc0 + jj);
            lds[b*JCD + jj+0] = v.x; lds[b*JCD + jj+1] = v.y;
            lds[b*JCD + jj+2] = v.z; lds[b*JCD + jj+3] = v.w;
        }
        __syncthreads();

        const int c4 = t & 63;                // 4-col group
        const int b0 = (t >> 6) * 4;          // 4-batch group
        const int k4 = k0 + c4*4;
        float4 acc[4];
        #pragma unroll
        for (int bi = 0; bi < 4; ++bi) acc[bi] = make_float4(0.f,0.f,0.f,0.f);

        #pragma unroll 2
        for (int j = 0; j < JCD; j += 4) {
            const float4 w0 = *(const float4*)(w + (size_t)(HH + jc0 + j+0)*HH + k4);
            const float4 w1 = *(const float4*)(w + (size_t)(HH + jc0 + j+1)*HH + k4);
            const float4 w2 = *(const float4*)(w + (size_t)(HH + jc0 + j+2)*HH + k4);
            const float4 w3 = *(const float4*)(w + (size_t)(HH + jc0 + j+3)*HH + k4);
            #pragma unroll
            for (int bi = 0; bi < 4; ++bi) {
                const float d0 = lds[(b0+bi)*JCD + j+0];
                const float d1 = lds[(b0+bi)*JCD + j+1];
                const float d2 = lds[(b0+bi)*JCD + j+2];
                const float d3 = lds[(b0+bi)*JCD + j+3];
                acc[bi].x += d0*w0.x; acc[bi].y += d0*w0.y; acc[bi].z += d0*w0.z; acc[bi].w += d0*w0.w;
                acc[bi].x += d1*w1.x; acc[bi].y += d1*w1.y; acc[bi].z += d1*w1.z; acc[bi].w += d1*w1.w;
                acc[bi].x += d2*w2.x; acc[bi].y += d2*w2.y; acc[bi].z += d2*w2.z; acc[bi].w += d2*w2.w;
                acc[bi].x += d3*w3.x; acc[bi].y += d3*w3.y; acc[bi].z += d3*w3.z; acc[bi].w += d3*w3.w;
            }
        }
        #pragma unroll
        for (int bi = 0; bi < 4; ++bi)
            *(float4*)(dp + ((size_t)cd*BB + b0 + bi)*QQ + q0 + c4*4) = acc[bi];
    }
}

// ---------------- Stage 2: reduce partials + gates -> h_last ----------------
// grid = (HH/256 = 4, BB), block = 256.
template<int CH, int CD>
__global__ __launch_bounds__(256, 2) void k_cell(
    const float* __restrict__ hp, const float* __restrict__ dp,
    const float* __restrict__ c0, float* __restrict__ hlast)
{
    __shared__ float4 p[4][64];
    const int t    = threadIdx.x;
    const int kblk = blockIdx.x;
    const int b    = blockIdx.y;
    const int g    = t >> 6;
    const int i    = t & 63;
    const int q    = g*HH + kblk*256 + i*4;

    float4 s = make_float4(0.f,0.f,0.f,0.f);
    #pragma unroll 8
    for (int ch = 0; ch < CH; ++ch) {
        const float4 v = *(const float4*)(hp + (size_t)ch*QQ + q);
        s.x += v.x; s.y += v.y; s.z += v.z; s.w += v.w;
    }
    #pragma unroll 8
    for (int cd = 0; cd < CD; ++cd) {
        const float4 v = *(const float4*)(dp + ((size_t)cd*BB + b)*QQ + q);
        s.x += v.x; s.y += v.y; s.z += v.z; s.w += v.w;
    }
    p[g][i] = s;
    __syncthreads();

    if (t < 64) {
        const float4 gf = p[0][t], gi = p[1][t], gc = p[2][t], go = p[3][t];
        const float4 cv = *(const float4*)(c0 + kblk*256 + t*4);
        float4 h;
        { const float f=1.f/(1.f+expf(-gf.x)), ii=1.f/(1.f+expf(-gi.x)), cg=tanhf(gc.x), o=1.f/(1.f+expf(-go.x)); h.x=o*tanhf(f*cv.x+ii*cg); }
        { const float f=1.f/(1.f+expf(-gf.y)), ii=1.f/(1.f+expf(-gi.y)), cg=tanhf(gc.y), o=1.f/(1.f+expf(-go.y)); h.y=o*tanhf(f*cv.y+ii*cg); }
        { const float f=1.f/(1.f+expf(-gf.z)), ii=1.f/(1.f+expf(-gi.z)), cg=tanhf(gc.z), o=1.f/(1.f+expf(-go.z)); h.z=o*tanhf(f*cv.z+ii*cg); }
        { const float f=1.f/(1.f+expf(-gf.w)), ii=1.f/(1.f+expf(-gi.w)), cg=tanhf(gc.w), o=1.f/(1.f+expf(-go.w)); h.w=o*tanhf(f*cv.w+ii*cg); }
        *(float4*)(hlast + (size_t)b*HH + kblk*256 + t*4) = h;
    }
}

// ---------------- Stage 3a: fc partial GEMM (k-split, KCN=8) ----------------
// grid = (CC/FCB = 125, KCN = 8), block = 256. KS=128 k per chunk; LDS 21 KB
// -> high occupancy. Pad +2 keeps float2 reads 8B-aligned; hs read is 2-way
// bank aliasing (free), wl read is broadcast. Partial -> pl[(kc*BB+b)*CC + c].
__global__ __launch_bounds__(256) void k_fc_part(
    const float* __restrict__ hlast, const float* __restrict__ fcw,
    float* __restrict__ pl)
{
    __shared__ float hs[BB][KS+2];
    __shared__ float wl[FCB][KS+2];
    const int t  = threadIdx.x;
    const int c0 = blockIdx.x * FCB;
    const int kc = blockIdx.y;
    const int k0 = kc*KS;
    const int b  = t & 31;
    const int cl = t >> 5;
    const int c  = c0 + cl;

    for (int l = t; l < BB*(KS/4); l += 256) {   // 1024 slots, 4 iters
        const int bb = l >> 5, kk = l & 31;
        const float4 v = *(const float4*)(hlast + (size_t)bb*HH + k0 + kk*4);
        *(float2*)&hs[bb][kk*4+0] = make_float2(v.x, v.y);
        *(float2*)&hs[bb][kk*4+2] = make_float2(v.z, v.w);
    }
    for (int l = t; l < FCB*(KS/4); l += 256) {  // 256 slots, 1 iter
        const int cc = l >> 5, kk = l & 31;
        const float4 v = *(const float4*)(fcw + (size_t)(c0+cc)*HH + k0 + kk*4);
        *(float2*)&wl[cc][kk*4+0] = make_float2(v.x, v.y);
        *(float2*)&wl[cc][kk*4+2] = make_float2(v.z, v.w);
    }
    __syncthreads();

    float acc = 0.f;
    #pragma unroll 16
    for (int k2 = 0; k2 < KS/2; ++k2) {
        const float2 h2 = *(const float2*)&hs[b][k2*2];
        const float2 w2 = *(const float2*)&wl[cl][k2*2];
        acc += h2.x*w2.x + h2.y*w2.y;
    }
    pl[((size_t)kc*BB + b)*CC + c] = acc;
}

// ---------------- Stage 3b: reduce k-split + bias + relu + log_softmax ----------------
// grid = (BB), block = 256.
__global__ __launch_bounds__(256) void k_lsm(
    const float* __restrict__ pl, const float* __restrict__ fcb,
    float* __restrict__ out)
{
    __shared__ float red[8];
    const int b = blockIdx.x, t = threadIdx.x;
    float v[4]; float vmax = -1e30f;
    #pragma unroll
    for (int ci = 0; ci < 4; ++ci) {
        const int c = t + ci*256;
        if (c < CC) {
            float s = fcb[c];
            #pragma unroll
            for (int kc = 0; kc < KCN; ++kc)
                s += pl[((size_t)kc*BB + b)*CC + c];
            v[ci] = fmaxf(s, 0.f);
            vmax = fmaxf(vmax, v[ci]);
        } else v[ci] = -1e30f;
    }
    for (int o = 32; o > 0; o >>= 1) vmax = fmaxf(vmax, __shfl_down(vmax, o, 64));
    const int lane = t & 63, wid = t >> 6;
    if (lane == 0) red[wid] = vmax;
    __syncthreads();
    if (t == 0) red[4] = fmaxf(fmaxf(red[0], red[1]), fmaxf(red[2], red[3]));
    __syncthreads();
    const float m = red[4];
    float se = 0.f;
    #pragma unroll
    for (int ci = 0; ci < 4; ++ci) {
        const int c = t + ci*256;
        if (c < CC) se += expf(v[ci] - m);
    }
    for (int o = 32; o > 0; o >>= 1) se += __shfl_down(se, o, 64);
    if (lane == 0) red[wid] = se;
    __syncthreads();
    if (t == 0) red[5] = m + logf(red[0] + red[1] + red[2] + red[3]);
    __syncthreads();
    const float lse = red[5];
    #pragma unroll
    for (int ci = 0; ci < 4; ++ci) {
        const int c = t + ci*256;
        if (c < CC) out[(size_t)b*CC + c] = v[ci] - lse;
    }
}

extern "C" void kernel_launch(void* const* d_in, const int* in_sizes, int n_in,
                              void* d_out, int out_size, void* d_ws, size_t ws_size,
                              hipStream_t stream) {
    const float* data = (const float*)d_in[0];
    const float* h0   = (const float*)d_in[1];
    const float* c0   = (const float*)d_in[2];
    const float* wf   = (const float*)d_in[3];
    const float* wi   = (const float*)d_in[4];
    const float* wc   = (const float*)d_in[5];
    const float* wo   = (const float*)d_in[6];
    const float* fcw  = (const float*)d_in[7];
    const float* fcb  = (const float*)d_in[8];
    float* out = (float*)d_out;

    // Config A: CH_H=32 (JCH=32), CH_D=16 (JCD=32) -> ~9.7 MB ws.
    // Config B: CH_H=32 (JCH=32), CH_D=4  (JCD=128) -> ~3.7 MB ws (fallback).
    const size_t needA = ((size_t)32*QQ + (size_t)16*BB*QQ + (size_t)BB*HH + (size_t)KCN*BB*CC) * 4;
    const bool cfgA = (ws_size >= needA);

    float* ws = (float*)d_ws;
    if (cfgA) {
        float* hp = ws;                               // 32*QQ
        float* dp = hp + (size_t)32*QQ;               // 16*BB*QQ
        float* hl = dp + (size_t)16*BB*QQ;            // BB*HH
        float* pl = hl + (size_t)BB*HH;               // KCN*BB*CC
        k_gates<32,32,32,16><<<dim3(2*32 + 16*16), 512, 0, stream>>>(data, h0, wf, wi, wc, wo, hp, dp);
        k_cell<32,16><<<dim3(HH/256, BB), 256, 0, stream>>>(hp, dp, c0, hl);
        k_fc_part<<<dim3(CC/FCB, KCN), 256, 0, stream>>>(hl, fcw, pl);
        k_lsm<<<dim3(BB), 256, 0, stream>>>(pl, fcb, out);
    } else {
        float* hp = ws;                               // 32*QQ
        float* dp = hp + (size_t)32*QQ;               // 4*BB*QQ
        float* hl = dp + (size_t)4*BB*QQ;             // BB*HH
        float* pl = hl + (size_t)BB*HH;               // KCN*BB*CC
        k_gates<32,32,128,4><<<dim3(2*32 + 16*4), 512, 0, stream>>>(data, h0, wf, wi, wc, wo, hp, dp);
        k_cell<32,4><<<dim3(HH/256, BB), 256, 0, stream>>>(hp, dp, c0, hl);
        k_fc_part<<<dim3(CC/FCB, KCN), 256, 0, stream>>>(hl, fcw, pl);
        k_lsm<<<dim3(BB), 256, 0, stream>>>(pl, fcb, out);
    }
}